// Round 3
// baseline (850.380 us; speedup 1.0000x reference)
//
#include <hip/hip_runtime.h>
#include <hip/hip_bf16.h>

#define N_SRC  200000
#define N_MIDN 40000
#define N_DSTN 8000
#define RREL   4
#define E1N    1000000
#define E2N    200000
#define CAP    96   // ELL capacity; mean degree 25, P(overflow) ~ 3e-9/node

typedef __attribute__((ext_vector_type(8))) short bf16x8;
typedef __attribute__((ext_vector_type(4))) float f32x4;
typedef __attribute__((ext_vector_type(4))) unsigned short u16x4;

__device__ __forceinline__ unsigned short f2bf(float f) {
    unsigned int u = __float_as_uint(f);
    u = (u + 0x7FFFu + ((u >> 16) & 1u)) >> 16;   // RNE
    return (unsigned short)u;
}

__device__ __forceinline__ void gload_lds16(const void* g, void* l) {
    __builtin_amdgcn_global_load_lds((const __attribute__((address_space(1))) void*)g,
                                     (__attribute__((address_space(3))) void*)l, 16, 0, 0);
}

// ---------------------------------------------------------------------------
// ELL build: 8 edges/thread -> 8 independent device atomics in flight.
// (1 edge/thread was latency-bound: ~25 outstanding atomics/CU -> 337 us)
// epr % 8 == 0, so an 8-edge group never crosses a relation boundary.
// ---------------------------------------------------------------------------
__global__ __launch_bounds__(256) void fill_kernel(
    const int* __restrict__ src, const int* __restrict__ dst,
    int* __restrict__ cnt, int* __restrict__ ell,
    int epr, int ndst)
{
    int i = (blockIdx.x * 256 + threadIdx.x) * 8;
    if (i >= RREL * epr) return;
    int4 sa = *(const int4*)&src[i];
    int4 sb = *(const int4*)&src[i + 4];
    int4 da = *(const int4*)&dst[i];
    int4 db = *(const int4*)&dst[i + 4];
    int b = (i / epr) * ndst;
    int n0 = b + da.x, n1 = b + da.y, n2 = b + da.z, n3 = b + da.w;
    int n4 = b + db.x, n5 = b + db.y, n6 = b + db.z, n7 = b + db.w;
    int t0 = atomicAdd(&cnt[n0], 1);
    int t1 = atomicAdd(&cnt[n1], 1);
    int t2 = atomicAdd(&cnt[n2], 1);
    int t3 = atomicAdd(&cnt[n3], 1);
    int t4 = atomicAdd(&cnt[n4], 1);
    int t5 = atomicAdd(&cnt[n5], 1);
    int t6 = atomicAdd(&cnt[n6], 1);
    int t7 = atomicAdd(&cnt[n7], 1);
    if (t0 < CAP) ell[n0 * CAP + t0] = sa.x;
    if (t1 < CAP) ell[n1 * CAP + t1] = sa.y;
    if (t2 < CAP) ell[n2 * CAP + t2] = sa.z;
    if (t3 < CAP) ell[n3 * CAP + t3] = sa.w;
    if (t4 < CAP) ell[n4 * CAP + t4] = sb.x;
    if (t5 < CAP) ell[n5 * CAP + t5] = sb.y;
    if (t6 < CAP) ell[n6 * CAP + t6] = sb.z;
    if (t7 < CAP) ell[n7 * CAP + t7] = sb.w;
}

// ---------------------------------------------------------------------------
// x (fp32 [N][256]) -> xb (bf16, per-row 16B-chunk XOR-swizzled: c ^= row&7)
// ---------------------------------------------------------------------------
__global__ __launch_bounds__(256) void convx_kernel(
    const float* __restrict__ x, unsigned short* __restrict__ xb)
{
    int id  = blockIdx.x * 256 + threadIdx.x;
    int row = id >> 5;
    int c   = id & 31;
    const float4* xp = (const float4*)(x + ((size_t)row << 8) + (c << 3));
    float4 a = xp[0], b = xp[1];
    u16x4 o0, o1;
    o0.x = f2bf(a.x); o0.y = f2bf(a.y); o0.z = f2bf(a.z); o0.w = f2bf(a.w);
    o1.x = f2bf(b.x); o1.y = f2bf(b.y); o1.z = f2bf(b.z); o1.w = f2bf(b.w);
    int cs = c ^ (row & 7);
    u16x4* op = (u16x4*)(xb + ((size_t)row << 8) + (cs << 3));
    op[0] = o0; op[1] = o1;
}

// ---------------------------------------------------------------------------
// W [R][K][128] fp32 -> Wt [R*128][K] bf16 (transposed, k-contiguous)
// ---------------------------------------------------------------------------
template<int K>
__global__ __launch_bounds__(256) void convw_kernel(
    const float* __restrict__ W, unsigned short* __restrict__ Wt)
{
    int id = blockIdx.x * 256 + threadIdx.x;
    if (id >= RREL * K * 128) return;
    int n  = id & 127;
    int rk = id >> 7;            // r*K + k
    int k  = rk & (K - 1);
    int r  = rk / K;
    Wt[(size_t)(r * 128 + n) * K + k] = f2bf(W[id]);
}

// ---------------------------------------------------------------------------
// GEMM: Ab (bf16 swizzled [Mpad][K]) x Wt[r] ([128][K] bf16) -> Mout bf16 [M][512]
// block 256 = 4 waves, tile 128x128, full K in LDS (A only), B from global (L2)
// ---------------------------------------------------------------------------
template<int K>
__global__ __launch_bounds__(256, (K == 128) ? 4 : 2) void gemm_kernel(
    const unsigned short* __restrict__ Ab,
    const unsigned short* __restrict__ Wt,
    unsigned short* __restrict__ Mout, int M)
{
    __shared__ unsigned short As[128 * K];

    const int r    = blockIdx.x;
    const int m0   = blockIdx.y * 128;
    const int tid  = threadIdx.x;
    const int lane = tid & 63;
    const int wave = tid >> 6;

    const char* gp = (const char*)Ab + (size_t)m0 * (K * 2) + wave * 1024 + lane * 16;
    char* lp = (char*)As + wave * 1024;
    #pragma unroll
    for (int j = 0; j < K / 16; ++j)
        gload_lds16(gp + j * 4096, lp + j * 4096);
    __syncthreads();

    const int wm   = (wave & 1) * 64;
    const int wn   = (wave >> 1) * 64;
    const int lr   = lane & 15;
    const int kg   = lane >> 4;
    const int xorv = (lr & 7) << 4;
    const unsigned short* Wr = Wt + (size_t)(r * 128) * K;
    const char* Asb = (const char*)As;

    f32x4 acc[4][4] = {};
    #pragma unroll 2
    for (int kk = 0; kk < K; kk += 32) {
        bf16x8 af[4], bv[4];
        const int kb = (kk * 2 + kg * 16) ^ xorv;
        #pragma unroll
        for (int mi = 0; mi < 4; ++mi)
            af[mi] = *(const bf16x8*)(Asb + (wm + mi * 16 + lr) * (K * 2) + kb);
        #pragma unroll
        for (int ni = 0; ni < 4; ++ni)
            bv[ni] = *(const bf16x8*)&Wr[(size_t)(wn + ni * 16 + lr) * K + kk + kg * 8];
        #pragma unroll
        for (int mi = 0; mi < 4; ++mi)
            #pragma unroll
            for (int ni = 0; ni < 4; ++ni)
                acc[mi][ni] = __builtin_amdgcn_mfma_f32_16x16x32_bf16(
                    af[mi], bv[ni], acc[mi][ni], 0, 0, 0);
    }

    const int rowoff = (lane >> 4) * 4;
    #pragma unroll
    for (int mi = 0; mi < 4; ++mi) {
        #pragma unroll
        for (int j = 0; j < 4; ++j) {
            int grow = m0 + wm + mi * 16 + rowoff + j;
            if (grow < M) {
                #pragma unroll
                for (int ni = 0; ni < 4; ++ni)
                    Mout[(size_t)grow * 512 + r * 128 + wn + ni * 16 + lr]
                        = f2bf(acc[mi][ni][j]);
            }
        }
    }
}

// ---------------------------------------------------------------------------
// Gather: block per dst node, wave w handles relation w.
// ---------------------------------------------------------------------------
template<bool OUT_F32>
__global__ __launch_bounds__(256) void gather_kernel(
    const unsigned short* __restrict__ Mt,   // [n_src_side][512] bf16
    const int* __restrict__ ell, const int* __restrict__ cnt,
    const float* __restrict__ bias,          // [R][128]
    void* __restrict__ outp, int ndst)
{
    __shared__ float red[RREL][128];
    const int node = blockIdx.x;
    const int lane = threadIdx.x & 63;
    const int r    = threadIdx.x >> 6;
    const int idx  = r * ndst + node;
    const int c    = cnt[idx];
    const int deg  = c < CAP ? c : CAP;
    const int base = idx * CAP;
    const int coff = r * 128 + lane * 2;

    float ax = 0.f, ay = 0.f;
    int e = 0;
    for (; e + 4 <= deg; e += 4) {
        int4 ss = *(const int4*)&ell[base + e];
        unsigned int v0 = *(const unsigned int*)&Mt[(size_t)ss.x * 512 + coff];
        unsigned int v1 = *(const unsigned int*)&Mt[(size_t)ss.y * 512 + coff];
        unsigned int v2 = *(const unsigned int*)&Mt[(size_t)ss.z * 512 + coff];
        unsigned int v3 = *(const unsigned int*)&Mt[(size_t)ss.w * 512 + coff];
        ax += __uint_as_float(v0 << 16) + __uint_as_float(v1 << 16)
            + __uint_as_float(v2 << 16) + __uint_as_float(v3 << 16);
        ay += __uint_as_float(v0 & 0xFFFF0000u) + __uint_as_float(v1 & 0xFFFF0000u)
            + __uint_as_float(v2 & 0xFFFF0000u) + __uint_as_float(v3 & 0xFFFF0000u);
    }
    for (; e < deg; ++e) {
        int s = ell[base + e];
        unsigned int v = *(const unsigned int*)&Mt[(size_t)s * 512 + coff];
        ax += __uint_as_float(v << 16);
        ay += __uint_as_float(v & 0xFFFF0000u);
    }
    float norm = c > 0 ? 1.0f / (float)c : 0.0f;
    red[r][lane * 2]     = ax * norm;
    red[r][lane * 2 + 1] = ay * norm;
    __syncthreads();

    const int t = threadIdx.x;
    if (t < 128) {
        float s = red[0][t] + red[1][t] + red[2][t] + red[3][t]
                + bias[t] + bias[128 + t] + bias[256 + t] + bias[384 + t];
        if constexpr (OUT_F32) {
            ((float*)outp)[node * 128 + t] = s;
        } else {
            int cs = ((t >> 3) ^ (node & 7)) << 3;           // swizzled h layout
            ((unsigned short*)outp)[node * 128 + cs + (t & 7)] = f2bf(s);
        }
    }
}

// ---------------------------------------------------------------------------
extern "C" void kernel_launch(void* const* d_in, const int* in_sizes, int n_in,
                              void* d_out, int out_size, void* d_ws, size_t ws_size,
                              hipStream_t stream)
{
    const float* x  = (const float*)d_in[0];
    const float* W1 = (const float*)d_in[1];
    const float* b1 = (const float*)d_in[2];
    const float* W2 = (const float*)d_in[3];
    const float* b2 = (const float*)d_in[4];
    const int* src1 = (const int*)d_in[5];
    const int* dst1 = (const int*)d_in[6];
    const int* src2 = (const int*)d_in[7];
    const int* dst2 = (const int*)d_in[8];

    char* p = (char*)d_ws;
    auto alloc = [&](size_t bytes) {
        char* q = p; p += (bytes + 255) & ~(size_t)255; return q;
    };
    unsigned short* xb   = (unsigned short*)alloc((size_t)(N_SRC + 64) * 256 * 2);  // 102.4 MB
    unsigned short* m1   = (unsigned short*)alloc((size_t)N_SRC * 512 * 2);         // 204.8 MB
    int*            ell1 = (int*)alloc((size_t)RREL * N_MIDN * CAP * 4);            //  61.4 MB
    int*            cnt1 = (int*)alloc((size_t)RREL * N_MIDN * 4);
    unsigned short* h    = (unsigned short*)alloc((size_t)(N_MIDN + 64) * 128 * 2); //  10.3 MB
    unsigned short* wt1  = (unsigned short*)alloc((size_t)RREL * 128 * 256 * 2);
    unsigned short* wt2  = (unsigned short*)alloc((size_t)RREL * 128 * 128 * 2);
    // Layer-2 scratch aliases xb (xb dead after gemm1):
    char* q2 = (char*)xb;
    unsigned short* m2   = (unsigned short*)q2; q2 += (size_t)N_MIDN * 512 * 2;     //  41.0 MB
    int*            ell2 = (int*)q2;            q2 += (size_t)RREL * N_DSTN * CAP * 4;
    int*            cnt2 = (int*)q2;

    hipMemsetAsync(cnt1, 0, (size_t)RREL * N_MIDN * 4, stream);
    convw_kernel<256><<<512, 256, 0, stream>>>(W1, wt1);
    convw_kernel<128><<<256, 256, 0, stream>>>(W2, wt2);
    convx_kernel<<<(N_SRC * 32) / 256, 256, 0, stream>>>(x, xb);
    fill_kernel<<<(RREL * E1N / 8 + 255) / 256, 256, 0, stream>>>(src1, dst1, cnt1, ell1, E1N, N_MIDN);

    gemm_kernel<256><<<dim3(RREL, (N_SRC + 127) / 128), 256, 0, stream>>>(xb, wt1, m1, N_SRC);
    gather_kernel<false><<<N_MIDN, 256, 0, stream>>>(m1, ell1, cnt1, b1, (void*)h, N_MIDN);

    hipMemsetAsync(cnt2, 0, (size_t)RREL * N_DSTN * 4, stream);
    fill_kernel<<<(RREL * E2N / 8 + 255) / 256, 256, 0, stream>>>(src2, dst2, cnt2, ell2, E2N, N_DSTN);

    gemm_kernel<128><<<dim3(RREL, (N_MIDN + 127) / 128), 256, 0, stream>>>(h, wt2, m2, N_MIDN);
    gather_kernel<true><<<N_DSTN, 256, 0, stream>>>(m2, ell2, cnt2, b2, d_out, N_DSTN);
}

// Round 4
// 687.203 us; speedup vs baseline: 1.2375x; 1.2375x over previous
//
#include <hip/hip_runtime.h>
#include <hip/hip_bf16.h>

#define N_SRC  200000
#define N_MIDN 40000
#define N_DSTN 8000
#define RREL   4
#define E1N    1000000
#define E2N    200000
#define CAP    96    // ELL capacity; mean degree 25, overflow prob negligible
#define EPB    8192  // edges per count/scatter block

typedef __attribute__((ext_vector_type(8))) short bf16x8;
typedef __attribute__((ext_vector_type(4))) float f32x4;
typedef __attribute__((ext_vector_type(4))) unsigned short u16x4;

__device__ __forceinline__ unsigned short f2bf(float f) {
    unsigned int u = __float_as_uint(f);
    u = (u + 0x7FFFu + ((u >> 16) & 1u)) >> 16;   // RNE
    return (unsigned short)u;
}

__device__ __forceinline__ void gload_lds16(const void* g, void* l) {
    __builtin_amdgcn_global_load_lds((const __attribute__((address_space(1))) void*)g,
                                     (__attribute__((address_space(3))) void*)l, 16, 0, 0);
}

// ---------------------------------------------------------------------------
// Phase 1: per-(relation, 8K-edge block) LDS byte histogram of dst.
// rank8[e] = edge's rank among same-dst edges of this block (LDS atomic return).
// hist[(r*nb+b)*ndst4 + w] = packed 4x u8 counts. NO device atomics.
// ---------------------------------------------------------------------------
__global__ __launch_bounds__(256) void count_kernel(
    const int* __restrict__ dst, unsigned char* __restrict__ rank8,
    unsigned int* __restrict__ hist, int epr, int ndst4, int nb)
{
    __shared__ unsigned int cnt4[10240];   // up to 40960 nodes as packed u8
    const int r = blockIdx.y, b = blockIdx.x;
    for (int i = threadIdx.x; i < ndst4; i += 256) cnt4[i] = 0;
    __syncthreads();
    const int e0 = b * EPB;
    const int ne = min(EPB, epr - e0);
    const int* dp = dst + (size_t)r * epr + e0;
    unsigned char* rp = rank8 + (size_t)r * epr + e0;
    for (int i = threadIdx.x; i < ne; i += 256) {
        int d = dp[i];
        unsigned int sh = (d & 3) * 8;
        unsigned int old = atomicAdd(&cnt4[d >> 2], 1u << sh);   // LDS atomic
        rp[i] = (unsigned char)((old >> sh) & 0xFFu);
    }
    __syncthreads();
    unsigned int* hp = hist + ((size_t)r * nb + b) * ndst4;
    for (int i = threadIdx.x; i < ndst4; i += 256) hp[i] = cnt4[i];
}

// ---------------------------------------------------------------------------
// Phase 2: per-(r,node) serial scan over the nb block-histograms.
// Rewrites hist bytes in place as "prefix before block b"; cnt = true degree.
// Reads/writes coalesce across threads (consecutive node bytes).
// ---------------------------------------------------------------------------
__global__ __launch_bounds__(256) void scan_kernel(
    unsigned int* __restrict__ hist, int* __restrict__ cnt,
    int ndst, int ndst4, int nb)
{
    int id = blockIdx.x * 256 + threadIdx.x;
    if (id >= RREL * ndst) return;
    int r = id / ndst;
    int node = id - r * ndst;
    unsigned char* hb = (unsigned char*)hist;
    const size_t stride = (size_t)ndst4 * 4;
    unsigned char* p0 = hb + (size_t)r * nb * stride + node;
    unsigned int run = 0;
    for (int b = 0; b < nb; ++b) {
        unsigned char* pp = p0 + (size_t)b * stride;
        unsigned int c = *pp;
        *pp = (unsigned char)run;          // degree per node ~25, fits u8
        run += c;
    }
    cnt[id] = (int)run;                     // true (uncapped) degree
}

// ---------------------------------------------------------------------------
// Phase 3: slot = rank8[e] + prefix[dst] (prefix slice staged in LDS);
// one scattered 4B store per edge, no atomics, no dependent chain.
// ---------------------------------------------------------------------------
__global__ __launch_bounds__(256) void scatter_kernel(
    const int* __restrict__ src, const int* __restrict__ dst,
    const unsigned char* __restrict__ rank8, const unsigned int* __restrict__ hist,
    int* __restrict__ ell, int epr, int ndst4, int nb)
{
    __shared__ unsigned int pre4[10240];
    const int r = blockIdx.y, b = blockIdx.x;
    const unsigned int* hp = hist + ((size_t)r * nb + b) * ndst4;
    for (int i = threadIdx.x; i < ndst4; i += 256) pre4[i] = hp[i];
    __syncthreads();
    const int e0 = b * EPB;
    const int ne = min(EPB, epr - e0);
    const size_t eb = (size_t)r * epr + e0;
    const unsigned char* pre = (const unsigned char*)pre4;
    const int ndst = ndst4 * 4;
    for (int i = threadIdx.x; i < ne; i += 256) {
        int d = dst[eb + i];
        int s = src[eb + i];
        int slot = (int)rank8[eb + i] + (int)pre[d];
        if (slot < CAP) ell[((size_t)r * ndst + d) * CAP + slot] = s;
    }
}

// ---------------------------------------------------------------------------
// x (fp32 [N][256]) -> xb (bf16, per-row 16B-chunk XOR-swizzled: c ^= row&7)
// ---------------------------------------------------------------------------
__global__ __launch_bounds__(256) void convx_kernel(
    const float* __restrict__ x, unsigned short* __restrict__ xb)
{
    int id  = blockIdx.x * 256 + threadIdx.x;
    int row = id >> 5;
    int c   = id & 31;
    const float4* xp = (const float4*)(x + ((size_t)row << 8) + (c << 3));
    float4 a = xp[0], b = xp[1];
    u16x4 o0, o1;
    o0.x = f2bf(a.x); o0.y = f2bf(a.y); o0.z = f2bf(a.z); o0.w = f2bf(a.w);
    o1.x = f2bf(b.x); o1.y = f2bf(b.y); o1.z = f2bf(b.z); o1.w = f2bf(b.w);
    int cs = c ^ (row & 7);
    u16x4* op = (u16x4*)(xb + ((size_t)row << 8) + (cs << 3));
    op[0] = o0; op[1] = o1;
}

// ---------------------------------------------------------------------------
// W [R][K][128] fp32 -> Wt [R*128][K] bf16 (transposed, k-contiguous)
// ---------------------------------------------------------------------------
template<int K>
__global__ __launch_bounds__(256) void convw_kernel(
    const float* __restrict__ W, unsigned short* __restrict__ Wt)
{
    int id = blockIdx.x * 256 + threadIdx.x;
    if (id >= RREL * K * 128) return;
    int n  = id & 127;
    int rk = id >> 7;            // r*K + k
    int k  = rk & (K - 1);
    int r  = rk / K;
    Wt[(size_t)(r * 128 + n) * K + k] = f2bf(W[id]);
}

// ---------------------------------------------------------------------------
// GEMM: Ab (bf16 swizzled [Mpad][K]) x Wt[r] ([128][K] bf16) -> Mout bf16 [M][512]
// ---------------------------------------------------------------------------
template<int K>
__global__ __launch_bounds__(256, (K == 128) ? 4 : 2) void gemm_kernel(
    const unsigned short* __restrict__ Ab,
    const unsigned short* __restrict__ Wt,
    unsigned short* __restrict__ Mout, int M)
{
    __shared__ unsigned short As[128 * K];

    const int r    = blockIdx.x;
    const int m0   = blockIdx.y * 128;
    const int tid  = threadIdx.x;
    const int lane = tid & 63;
    const int wave = tid >> 6;

    const char* gp = (const char*)Ab + (size_t)m0 * (K * 2) + wave * 1024 + lane * 16;
    char* lp = (char*)As + wave * 1024;
    #pragma unroll
    for (int j = 0; j < K / 16; ++j)
        gload_lds16(gp + j * 4096, lp + j * 4096);
    __syncthreads();

    const int wm   = (wave & 1) * 64;
    const int wn   = (wave >> 1) * 64;
    const int lr   = lane & 15;
    const int kg   = lane >> 4;
    const int xorv = (lr & 7) << 4;
    const unsigned short* Wr = Wt + (size_t)(r * 128) * K;
    const char* Asb = (const char*)As;

    f32x4 acc[4][4] = {};
    #pragma unroll 2
    for (int kk = 0; kk < K; kk += 32) {
        bf16x8 af[4], bv[4];
        const int kb = (kk * 2 + kg * 16) ^ xorv;
        #pragma unroll
        for (int mi = 0; mi < 4; ++mi)
            af[mi] = *(const bf16x8*)(Asb + (wm + mi * 16 + lr) * (K * 2) + kb);
        #pragma unroll
        for (int ni = 0; ni < 4; ++ni)
            bv[ni] = *(const bf16x8*)&Wr[(size_t)(wn + ni * 16 + lr) * K + kk + kg * 8];
        #pragma unroll
        for (int mi = 0; mi < 4; ++mi)
            #pragma unroll
            for (int ni = 0; ni < 4; ++ni)
                acc[mi][ni] = __builtin_amdgcn_mfma_f32_16x16x32_bf16(
                    af[mi], bv[ni], acc[mi][ni], 0, 0, 0);
    }

    const int rowoff = (lane >> 4) * 4;
    #pragma unroll
    for (int mi = 0; mi < 4; ++mi) {
        #pragma unroll
        for (int j = 0; j < 4; ++j) {
            int grow = m0 + wm + mi * 16 + rowoff + j;
            if (grow < M) {
                #pragma unroll
                for (int ni = 0; ni < 4; ++ni)
                    Mout[(size_t)grow * 512 + r * 128 + wn + ni * 16 + lr]
                        = f2bf(acc[mi][ni][j]);
            }
        }
    }
}

// ---------------------------------------------------------------------------
// Gather: block per dst node, wave w handles relation w.
// ---------------------------------------------------------------------------
template<bool OUT_F32>
__global__ __launch_bounds__(256) void gather_kernel(
    const unsigned short* __restrict__ Mt,   // [n_src_side][512] bf16
    const int* __restrict__ ell, const int* __restrict__ cnt,
    const float* __restrict__ bias,          // [R][128]
    void* __restrict__ outp, int ndst)
{
    __shared__ float red[RREL][128];
    const int node = blockIdx.x;
    const int lane = threadIdx.x & 63;
    const int r    = threadIdx.x >> 6;
    const int idx  = r * ndst + node;
    const int c    = cnt[idx];
    const int deg  = c < CAP ? c : CAP;
    const int base = idx * CAP;
    const int coff = r * 128 + lane * 2;

    float ax = 0.f, ay = 0.f;
    int e = 0;
    for (; e + 4 <= deg; e += 4) {
        int4 ss = *(const int4*)&ell[base + e];
        unsigned int v0 = *(const unsigned int*)&Mt[(size_t)ss.x * 512 + coff];
        unsigned int v1 = *(const unsigned int*)&Mt[(size_t)ss.y * 512 + coff];
        unsigned int v2 = *(const unsigned int*)&Mt[(size_t)ss.z * 512 + coff];
        unsigned int v3 = *(const unsigned int*)&Mt[(size_t)ss.w * 512 + coff];
        ax += __uint_as_float(v0 << 16) + __uint_as_float(v1 << 16)
            + __uint_as_float(v2 << 16) + __uint_as_float(v3 << 16);
        ay += __uint_as_float(v0 & 0xFFFF0000u) + __uint_as_float(v1 & 0xFFFF0000u)
            + __uint_as_float(v2 & 0xFFFF0000u) + __uint_as_float(v3 & 0xFFFF0000u);
    }
    for (; e < deg; ++e) {
        int s = ell[base + e];
        unsigned int v = *(const unsigned int*)&Mt[(size_t)s * 512 + coff];
        ax += __uint_as_float(v << 16);
        ay += __uint_as_float(v & 0xFFFF0000u);
    }
    float norm = c > 0 ? 1.0f / (float)c : 0.0f;
    red[r][lane * 2]     = ax * norm;
    red[r][lane * 2 + 1] = ay * norm;
    __syncthreads();

    const int t = threadIdx.x;
    if (t < 128) {
        float s = red[0][t] + red[1][t] + red[2][t] + red[3][t]
                + bias[t] + bias[128 + t] + bias[256 + t] + bias[384 + t];
        if constexpr (OUT_F32) {
            ((float*)outp)[node * 128 + t] = s;
        } else {
            int cs = ((t >> 3) ^ (node & 7)) << 3;           // swizzled h layout
            ((unsigned short*)outp)[node * 128 + cs + (t & 7)] = f2bf(s);
        }
    }
}

// ---------------------------------------------------------------------------
extern "C" void kernel_launch(void* const* d_in, const int* in_sizes, int n_in,
                              void* d_out, int out_size, void* d_ws, size_t ws_size,
                              hipStream_t stream)
{
    const float* x  = (const float*)d_in[0];
    const float* W1 = (const float*)d_in[1];
    const float* b1 = (const float*)d_in[2];
    const float* W2 = (const float*)d_in[3];
    const float* b2 = (const float*)d_in[4];
    const int* src1 = (const int*)d_in[5];
    const int* dst1 = (const int*)d_in[6];
    const int* src2 = (const int*)d_in[7];
    const int* dst2 = (const int*)d_in[8];

    char* p = (char*)d_ws;
    auto alloc = [&](size_t bytes) {
        char* q = p; p += (bytes + 255) & ~(size_t)255; return q;
    };
    unsigned short* xb   = (unsigned short*)alloc((size_t)(N_SRC + 64) * 256 * 2);  // 102.4 MB
    unsigned short* m1   = (unsigned short*)alloc((size_t)N_SRC * 512 * 2);         // 204.8 MB
    int*            ell1 = (int*)alloc((size_t)RREL * N_MIDN * CAP * 4);            //  61.4 MB
    int*            cnt1 = (int*)alloc((size_t)RREL * N_MIDN * 4);
    unsigned short* h    = (unsigned short*)alloc((size_t)(N_MIDN + 64) * 128 * 2); //  10.3 MB
    unsigned short* wt1  = (unsigned short*)alloc((size_t)RREL * 128 * 256 * 2);
    unsigned short* wt2  = (unsigned short*)alloc((size_t)RREL * 128 * 128 * 2);
    // Layer-2 scratch aliases xb (xb dead after gemm1):
    char* q2 = (char*)xb;
    unsigned short* m2   = (unsigned short*)q2; q2 += (size_t)N_MIDN * 512 * 2;     //  41.0 MB
    int*            ell2 = (int*)q2;            q2 += (size_t)RREL * N_DSTN * CAP * 4;
    int*            cnt2 = (int*)q2;
    // Fill scratch aliases m1 (m1 is written by gemm1 AFTER scatter1; dead
    // again after gather1, before count2 runs):
    const int NB1 = (E1N + EPB - 1) / EPB;   // 123
    const int NB2 = (E2N + EPB - 1) / EPB;   // 25
    unsigned int*  hist  = (unsigned int*)m1;                          // <= 19.7 MB
    unsigned char* rank8 = (unsigned char*)m1 + 24 * 1024 * 1024;      // 4 MB

    convw_kernel<256><<<512, 256, 0, stream>>>(W1, wt1);
    convw_kernel<128><<<256, 256, 0, stream>>>(W2, wt2);
    convx_kernel<<<(N_SRC * 32) / 256, 256, 0, stream>>>(x, xb);

    // layer-1 ELL build (atomic-free counting sort)
    count_kernel  <<<dim3(NB1, RREL), 256, 0, stream>>>(dst1, rank8, hist, E1N, N_MIDN / 4, NB1);
    scan_kernel   <<<(RREL * N_MIDN + 255) / 256, 256, 0, stream>>>(hist, cnt1, N_MIDN, N_MIDN / 4, NB1);
    scatter_kernel<<<dim3(NB1, RREL), 256, 0, stream>>>(src1, dst1, rank8, hist, ell1, E1N, N_MIDN / 4, NB1);

    gemm_kernel<256><<<dim3(RREL, (N_SRC + 127) / 128), 256, 0, stream>>>(xb, wt1, m1, N_SRC);
    gather_kernel<false><<<N_MIDN, 256, 0, stream>>>(m1, ell1, cnt1, b1, (void*)h, N_MIDN);

    // layer-2 ELL build (hist/rank8 reuse m1 space; ell2/cnt2 alias xb)
    count_kernel  <<<dim3(NB2, RREL), 256, 0, stream>>>(dst2, rank8, hist, E2N, N_DSTN / 4, NB2);
    scan_kernel   <<<(RREL * N_DSTN + 255) / 256, 256, 0, stream>>>(hist, cnt2, N_DSTN, N_DSTN / 4, NB2);
    scatter_kernel<<<dim3(NB2, RREL), 256, 0, stream>>>(src2, dst2, rank8, hist, ell2, E2N, N_DSTN / 4, NB2);

    gemm_kernel<128><<<dim3(RREL, (N_MIDN + 127) / 128), 256, 0, stream>>>(h, wt2, m2, N_MIDN);
    gather_kernel<true><<<N_DSTN, 256, 0, stream>>>(m2, ell2, cnt2, b2, d_out, N_DSTN);
}

// Round 5
// 661.259 us; speedup vs baseline: 1.2860x; 1.0392x over previous
//
#include <hip/hip_runtime.h>
#include <hip/hip_bf16.h>

#define N_SRC  200000
#define N_MIDN 40000
#define N_DSTN 8000
#define RREL   4
#define E1N    1000000
#define E2N    200000
#define CAP    96    // ELL capacity; mean degree 25, overflow prob negligible
#define EPB    8192  // edges per count/scatter block

typedef __attribute__((ext_vector_type(8))) short bf16x8;
typedef __attribute__((ext_vector_type(4))) float f32x4;
typedef __attribute__((ext_vector_type(4))) unsigned short u16x4;

__device__ __forceinline__ unsigned short f2bf(float f) {
    unsigned int u = __float_as_uint(f);
    u = (u + 0x7FFFu + ((u >> 16) & 1u)) >> 16;   // RNE
    return (unsigned short)u;
}

__device__ __forceinline__ float bflo(unsigned int u) { return __uint_as_float(u << 16); }
__device__ __forceinline__ float bfhi(unsigned int u) { return __uint_as_float(u & 0xFFFF0000u); }

__device__ __forceinline__ void gload_lds16(const void* g, void* l) {
    __builtin_amdgcn_global_load_lds((const __attribute__((address_space(1))) void*)g,
                                     (__attribute__((address_space(3))) void*)l, 16, 0, 0);
}

// ---------------------------------------------------------------------------
// Phase 1: per-(relation, 8K-edge block) LDS byte histogram of dst.
// rank8[e] = edge's rank among same-dst edges of this block (LDS atomic return).
// ---------------------------------------------------------------------------
__global__ __launch_bounds__(256) void count_kernel(
    const int* __restrict__ dst, unsigned char* __restrict__ rank8,
    unsigned int* __restrict__ hist, int epr, int ndst4, int nb)
{
    __shared__ unsigned int cnt4[10240];   // up to 40960 nodes as packed u8
    const int r = blockIdx.y, b = blockIdx.x;
    for (int i = threadIdx.x; i < ndst4; i += 256) cnt4[i] = 0;
    __syncthreads();
    const int e0 = b * EPB;
    const int ne = min(EPB, epr - e0);
    const int* dp = dst + (size_t)r * epr + e0;
    unsigned char* rp = rank8 + (size_t)r * epr + e0;
    for (int i = threadIdx.x; i < ne; i += 256) {
        int d = dp[i];
        unsigned int sh = (d & 3) * 8;
        unsigned int old = atomicAdd(&cnt4[d >> 2], 1u << sh);   // LDS atomic
        rp[i] = (unsigned char)((old >> sh) & 0xFFu);
    }
    __syncthreads();
    unsigned int* hp = hist + ((size_t)r * nb + b) * ndst4;
    for (int i = threadIdx.x; i < ndst4; i += 256) hp[i] = cnt4[i];
}

// ---------------------------------------------------------------------------
// Phase 2: per-(r,node) serial scan over the nb block-histograms.
// ---------------------------------------------------------------------------
__global__ __launch_bounds__(256) void scan_kernel(
    unsigned int* __restrict__ hist, int* __restrict__ cnt,
    int ndst, int ndst4, int nb)
{
    int id = blockIdx.x * 256 + threadIdx.x;
    if (id >= RREL * ndst) return;
    int r = id / ndst;
    int node = id - r * ndst;
    unsigned char* hb = (unsigned char*)hist;
    const size_t stride = (size_t)ndst4 * 4;
    unsigned char* p0 = hb + (size_t)r * nb * stride + node;
    unsigned int run = 0;
    for (int b = 0; b < nb; ++b) {
        unsigned char* pp = p0 + (size_t)b * stride;
        unsigned int c = *pp;
        *pp = (unsigned char)run;          // degree per node ~25, fits u8
        run += c;
    }
    cnt[id] = (int)run;                     // true (uncapped) degree
}

// ---------------------------------------------------------------------------
// Phase 3: slot = rank8[e] + prefix[dst]; scattered 4B store, no atomics.
// ---------------------------------------------------------------------------
__global__ __launch_bounds__(256) void scatter_kernel(
    const int* __restrict__ src, const int* __restrict__ dst,
    const unsigned char* __restrict__ rank8, const unsigned int* __restrict__ hist,
    int* __restrict__ ell, int epr, int ndst4, int nb)
{
    __shared__ unsigned int pre4[10240];
    const int r = blockIdx.y, b = blockIdx.x;
    const unsigned int* hp = hist + ((size_t)r * nb + b) * ndst4;
    for (int i = threadIdx.x; i < ndst4; i += 256) pre4[i] = hp[i];
    __syncthreads();
    const int e0 = b * EPB;
    const int ne = min(EPB, epr - e0);
    const size_t eb = (size_t)r * epr + e0;
    const unsigned char* pre = (const unsigned char*)pre4;
    const int ndst = ndst4 * 4;
    for (int i = threadIdx.x; i < ne; i += 256) {
        int d = dst[eb + i];
        int s = src[eb + i];
        int slot = (int)rank8[eb + i] + (int)pre[d];
        if (slot < CAP) ell[((size_t)r * ndst + d) * CAP + slot] = s;
    }
}

// ---------------------------------------------------------------------------
// x (fp32 [N][256]) -> xb (bf16, per-row 16B-chunk XOR-swizzled: c ^= row&7)
// ---------------------------------------------------------------------------
__global__ __launch_bounds__(256) void convx_kernel(
    const float* __restrict__ x, unsigned short* __restrict__ xb)
{
    int id  = blockIdx.x * 256 + threadIdx.x;
    int row = id >> 5;
    int c   = id & 31;
    const float4* xp = (const float4*)(x + ((size_t)row << 8) + (c << 3));
    float4 a = xp[0], b = xp[1];
    u16x4 o0, o1;
    o0.x = f2bf(a.x); o0.y = f2bf(a.y); o0.z = f2bf(a.z); o0.w = f2bf(a.w);
    o1.x = f2bf(b.x); o1.y = f2bf(b.y); o1.z = f2bf(b.z); o1.w = f2bf(b.w);
    int cs = c ^ (row & 7);
    u16x4* op = (u16x4*)(xb + ((size_t)row << 8) + (cs << 3));
    op[0] = o0; op[1] = o1;
}

// ---------------------------------------------------------------------------
// W [R][K][128] fp32 -> Wt [R*128][K] bf16 (transposed, k-contiguous)
// ---------------------------------------------------------------------------
template<int K>
__global__ __launch_bounds__(256) void convw_kernel(
    const float* __restrict__ W, unsigned short* __restrict__ Wt)
{
    int id = blockIdx.x * 256 + threadIdx.x;
    if (id >= RREL * K * 128) return;
    int n  = id & 127;
    int rk = id >> 7;            // r*K + k
    int k  = rk & (K - 1);
    int r  = rk / K;
    Wt[(size_t)(r * 128 + n) * K + k] = f2bf(W[id]);
}

// ---------------------------------------------------------------------------
// GEMM: Ab (bf16 swizzled [Mpad][K]) x Wt[r] ([128][K] bf16) -> Mout bf16 [M][512]
// ---------------------------------------------------------------------------
template<int K>
__global__ __launch_bounds__(256, (K == 128) ? 4 : 2) void gemm_kernel(
    const unsigned short* __restrict__ Ab,
    const unsigned short* __restrict__ Wt,
    unsigned short* __restrict__ Mout, int M)
{
    __shared__ unsigned short As[128 * K];

    const int r    = blockIdx.x;
    const int m0   = blockIdx.y * 128;
    const int tid  = threadIdx.x;
    const int lane = tid & 63;
    const int wave = tid >> 6;

    const char* gp = (const char*)Ab + (size_t)m0 * (K * 2) + wave * 1024 + lane * 16;
    char* lp = (char*)As + wave * 1024;
    #pragma unroll
    for (int j = 0; j < K / 16; ++j)
        gload_lds16(gp + j * 4096, lp + j * 4096);
    __syncthreads();

    const int wm   = (wave & 1) * 64;
    const int wn   = (wave >> 1) * 64;
    const int lr   = lane & 15;
    const int kg   = lane >> 4;
    const int xorv = (lr & 7) << 4;
    const unsigned short* Wr = Wt + (size_t)(r * 128) * K;
    const char* Asb = (const char*)As;

    f32x4 acc[4][4] = {};
    #pragma unroll 2
    for (int kk = 0; kk < K; kk += 32) {
        bf16x8 af[4], bv[4];
        const int kb = (kk * 2 + kg * 16) ^ xorv;
        #pragma unroll
        for (int mi = 0; mi < 4; ++mi)
            af[mi] = *(const bf16x8*)(Asb + (wm + mi * 16 + lr) * (K * 2) + kb);
        #pragma unroll
        for (int ni = 0; ni < 4; ++ni)
            bv[ni] = *(const bf16x8*)&Wr[(size_t)(wn + ni * 16 + lr) * K + kk + kg * 8];
        #pragma unroll
        for (int mi = 0; mi < 4; ++mi)
            #pragma unroll
            for (int ni = 0; ni < 4; ++ni)
                acc[mi][ni] = __builtin_amdgcn_mfma_f32_16x16x32_bf16(
                    af[mi], bv[ni], acc[mi][ni], 0, 0, 0);
    }

    const int rowoff = (lane >> 4) * 4;
    #pragma unroll
    for (int mi = 0; mi < 4; ++mi) {
        #pragma unroll
        for (int j = 0; j < 4; ++j) {
            int grow = m0 + wm + mi * 16 + rowoff + j;
            if (grow < M) {
                #pragma unroll
                for (int ni = 0; ni < 4; ++ni)
                    Mout[(size_t)grow * 512 + r * 128 + wn + ni * 16 + lr]
                        = f2bf(acc[mi][ni][j]);
            }
        }
    }
}

// ---------------------------------------------------------------------------
// Gather: block per dst node, wave w handles relation w.
// 8 edges/iter, lane-halves split across edge pairs (4 x dwordx2 in flight):
// lanes 0-31 carry the even edge's 128 dims (4 bf16/lane), lanes 32-63 the odd.
// ---------------------------------------------------------------------------
template<bool OUT_F32>
__global__ __launch_bounds__(256) void gather_kernel(
    const unsigned short* __restrict__ Mt,   // [n_src_side][512] bf16
    const int* __restrict__ ell, const int* __restrict__ cnt,
    const float* __restrict__ bias,          // [R][128]
    void* __restrict__ outp, int ndst)
{
    __shared__ float red[RREL][2][128];
    const int node = blockIdx.x;
    const int lane = threadIdx.x & 63;
    const int r    = threadIdx.x >> 6;
    const int half = lane >> 5;
    const int sub  = lane & 31;
    const int idx  = r * ndst + node;
    const int c    = cnt[idx];
    const int deg  = c < CAP ? c : CAP;
    const int base = idx * CAP;
    const int coff = r * 128 + sub * 4;      // element offset; 8B per lane

    float a0 = 0.f, a1 = 0.f, a2 = 0.f, a3 = 0.f;
    int e = 0;
    for (; e + 8 <= deg; e += 8) {
        int4 sa = *(const int4*)&ell[base + e];
        int4 sb = *(const int4*)&ell[base + e + 4];
        int sA = half ? sa.y : sa.x;
        int sB = half ? sa.w : sa.z;
        int sC = half ? sb.y : sb.x;
        int sD = half ? sb.w : sb.z;
        uint2 v0 = *(const uint2*)&Mt[(size_t)sA * 512 + coff];
        uint2 v1 = *(const uint2*)&Mt[(size_t)sB * 512 + coff];
        uint2 v2 = *(const uint2*)&Mt[(size_t)sC * 512 + coff];
        uint2 v3 = *(const uint2*)&Mt[(size_t)sD * 512 + coff];
        a0 += bflo(v0.x) + bflo(v1.x) + bflo(v2.x) + bflo(v3.x);
        a1 += bfhi(v0.x) + bfhi(v1.x) + bfhi(v2.x) + bfhi(v3.x);
        a2 += bflo(v0.y) + bflo(v1.y) + bflo(v2.y) + bflo(v3.y);
        a3 += bfhi(v0.y) + bfhi(v1.y) + bfhi(v2.y) + bfhi(v3.y);
    }
    for (; e < deg; e += 2) {
        int s0 = ell[base + e];
        int s1 = (e + 1 < deg) ? ell[base + e + 1] : -1;
        int s = half ? s1 : s0;
        if (s >= 0) {
            uint2 v = *(const uint2*)&Mt[(size_t)s * 512 + coff];
            a0 += bflo(v.x); a1 += bfhi(v.x);
            a2 += bflo(v.y); a3 += bfhi(v.y);
        }
    }
    float norm = c > 0 ? 1.0f / (float)c : 0.0f;
    red[r][half][sub * 4 + 0] = a0 * norm;
    red[r][half][sub * 4 + 1] = a1 * norm;
    red[r][half][sub * 4 + 2] = a2 * norm;
    red[r][half][sub * 4 + 3] = a3 * norm;
    __syncthreads();

    const int t = threadIdx.x;
    if (t < 128) {
        float s = red[0][0][t] + red[0][1][t] + red[1][0][t] + red[1][1][t]
                + red[2][0][t] + red[2][1][t] + red[3][0][t] + red[3][1][t]
                + bias[t] + bias[128 + t] + bias[256 + t] + bias[384 + t];
        if constexpr (OUT_F32) {
            ((float*)outp)[node * 128 + t] = s;
        } else {
            int cs = ((t >> 3) ^ (node & 7)) << 3;           // swizzled h layout
            ((unsigned short*)outp)[node * 128 + cs + (t & 7)] = f2bf(s);
        }
    }
}

// ---------------------------------------------------------------------------
extern "C" void kernel_launch(void* const* d_in, const int* in_sizes, int n_in,
                              void* d_out, int out_size, void* d_ws, size_t ws_size,
                              hipStream_t stream)
{
    const float* x  = (const float*)d_in[0];
    const float* W1 = (const float*)d_in[1];
    const float* b1 = (const float*)d_in[2];
    const float* W2 = (const float*)d_in[3];
    const float* b2 = (const float*)d_in[4];
    const int* src1 = (const int*)d_in[5];
    const int* dst1 = (const int*)d_in[6];
    const int* src2 = (const int*)d_in[7];
    const int* dst2 = (const int*)d_in[8];

    char* p = (char*)d_ws;
    auto alloc = [&](size_t bytes) {
        char* q = p; p += (bytes + 255) & ~(size_t)255; return q;
    };
    unsigned short* xb   = (unsigned short*)alloc((size_t)(N_SRC + 64) * 256 * 2);  // 102.4 MB
    unsigned short* m1   = (unsigned short*)alloc((size_t)N_SRC * 512 * 2);         // 204.8 MB
    int*            ell1 = (int*)alloc((size_t)RREL * N_MIDN * CAP * 4);            //  61.4 MB
    int*            cnt1 = (int*)alloc((size_t)RREL * N_MIDN * 4);
    unsigned short* h    = (unsigned short*)alloc((size_t)(N_MIDN + 64) * 128 * 2); //  10.3 MB
    unsigned short* wt1  = (unsigned short*)alloc((size_t)RREL * 128 * 256 * 2);
    unsigned short* wt2  = (unsigned short*)alloc((size_t)RREL * 128 * 128 * 2);
    // Layer-2 scratch aliases xb (xb dead after gemm1):
    char* q2 = (char*)xb;
    unsigned short* m2   = (unsigned short*)q2; q2 += (size_t)N_MIDN * 512 * 2;     //  41.0 MB
    int*            ell2 = (int*)q2;            q2 += (size_t)RREL * N_DSTN * CAP * 4;
    int*            cnt2 = (int*)q2;
    // Fill scratch aliases m1 (dead until gemm1 / after gather1):
    const int NB1 = (E1N + EPB - 1) / EPB;   // 123
    const int NB2 = (E2N + EPB - 1) / EPB;   // 25
    unsigned int*  hist  = (unsigned int*)m1;                          // <= 19.7 MB
    unsigned char* rank8 = (unsigned char*)m1 + 24 * 1024 * 1024;      // 4 MB

    convw_kernel<256><<<512, 256, 0, stream>>>(W1, wt1);
    convw_kernel<128><<<256, 256, 0, stream>>>(W2, wt2);
    convx_kernel<<<(N_SRC * 32) / 256, 256, 0, stream>>>(x, xb);

    // layer-1 ELL build (atomic-free counting sort)
    count_kernel  <<<dim3(NB1, RREL), 256, 0, stream>>>(dst1, rank8, hist, E1N, N_MIDN / 4, NB1);
    scan_kernel   <<<(RREL * N_MIDN + 255) / 256, 256, 0, stream>>>(hist, cnt1, N_MIDN, N_MIDN / 4, NB1);
    scatter_kernel<<<dim3(NB1, RREL), 256, 0, stream>>>(src1, dst1, rank8, hist, ell1, E1N, N_MIDN / 4, NB1);

    gemm_kernel<256><<<dim3(RREL, (N_SRC + 127) / 128), 256, 0, stream>>>(xb, wt1, m1, N_SRC);
    gather_kernel<false><<<N_MIDN, 256, 0, stream>>>(m1, ell1, cnt1, b1, (void*)h, N_MIDN);

    // layer-2 ELL build (hist/rank8 reuse m1 space; ell2/cnt2 alias xb)
    count_kernel  <<<dim3(NB2, RREL), 256, 0, stream>>>(dst2, rank8, hist, E2N, N_DSTN / 4, NB2);
    scan_kernel   <<<(RREL * N_DSTN + 255) / 256, 256, 0, stream>>>(hist, cnt2, N_DSTN, N_DSTN / 4, NB2);
    scatter_kernel<<<dim3(NB2, RREL), 256, 0, stream>>>(src2, dst2, rank8, hist, ell2, E2N, N_DSTN / 4, NB2);

    gemm_kernel<128><<<dim3(RREL, (N_MIDN + 127) / 128), 256, 0, stream>>>(h, wt2, m2, N_MIDN);
    gather_kernel<true><<<N_DSTN, 256, 0, stream>>>(m2, ell2, cnt2, b2, d_out, N_DSTN);
}

// Round 6
// 585.014 us; speedup vs baseline: 1.4536x; 1.1303x over previous
//
#include <hip/hip_runtime.h>
#include <hip/hip_bf16.h>

#define N_SRC  200000
#define N_MIDN 40000
#define N_DSTN 8000
#define RREL   4
#define E1N    1000000
#define E2N    200000
#define CAP    96    // ELL capacity; mean degree 25, overflow prob negligible
#define EPB    8192  // edges per count/scatter block

typedef __attribute__((ext_vector_type(8))) short bf16x8;
typedef __attribute__((ext_vector_type(4))) float f32x4;
typedef __attribute__((ext_vector_type(4))) unsigned short u16x4;

__device__ __forceinline__ unsigned short f2bf(float f) {
    unsigned int u = __float_as_uint(f);
    u = (u + 0x7FFFu + ((u >> 16) & 1u)) >> 16;   // RNE
    return (unsigned short)u;
}

__device__ __forceinline__ float bflo(unsigned int u) { return __uint_as_float(u << 16); }
__device__ __forceinline__ float bfhi(unsigned int u) { return __uint_as_float(u & 0xFFFF0000u); }

__device__ __forceinline__ void gload_lds16(const void* g, void* l) {
    __builtin_amdgcn_global_load_lds((const __attribute__((address_space(1))) void*)g,
                                     (__attribute__((address_space(3))) void*)l, 16, 0, 0);
}

// ---------------------------------------------------------------------------
// Phase 1: per-(relation, 8K-edge block) LDS byte histogram of dst.
// ---------------------------------------------------------------------------
__global__ __launch_bounds__(256) void count_kernel(
    const int* __restrict__ dst, unsigned char* __restrict__ rank8,
    unsigned int* __restrict__ hist, int epr, int ndst4, int nb)
{
    __shared__ unsigned int cnt4[10240];   // up to 40960 nodes as packed u8
    const int r = blockIdx.y, b = blockIdx.x;
    for (int i = threadIdx.x; i < ndst4; i += 256) cnt4[i] = 0;
    __syncthreads();
    const int e0 = b * EPB;
    const int ne = min(EPB, epr - e0);
    const int* dp = dst + (size_t)r * epr + e0;
    unsigned char* rp = rank8 + (size_t)r * epr + e0;
    for (int i = threadIdx.x; i < ne; i += 256) {
        int d = dp[i];
        unsigned int sh = (d & 3) * 8;
        unsigned int old = atomicAdd(&cnt4[d >> 2], 1u << sh);   // LDS atomic
        rp[i] = (unsigned char)((old >> sh) & 0xFFu);
    }
    __syncthreads();
    unsigned int* hp = hist + ((size_t)r * nb + b) * ndst4;
    for (int i = threadIdx.x; i < ndst4; i += 256) hp[i] = cnt4[i];
}

// ---------------------------------------------------------------------------
// Phase 2: per-(r,node) serial scan over the nb block-histograms.
// ---------------------------------------------------------------------------
__global__ __launch_bounds__(256) void scan_kernel(
    unsigned int* __restrict__ hist, int* __restrict__ cnt,
    int ndst, int ndst4, int nb)
{
    int id = blockIdx.x * 256 + threadIdx.x;
    if (id >= RREL * ndst) return;
    int r = id / ndst;
    int node = id - r * ndst;
    unsigned char* hb = (unsigned char*)hist;
    const size_t stride = (size_t)ndst4 * 4;
    unsigned char* p0 = hb + (size_t)r * nb * stride + node;
    unsigned int run = 0;
    for (int b = 0; b < nb; ++b) {
        unsigned char* pp = p0 + (size_t)b * stride;
        unsigned int c = *pp;
        *pp = (unsigned char)run;          // degree per node ~25, fits u8
        run += c;
    }
    cnt[id] = (int)run;                     // true (uncapped) degree
}

// ---------------------------------------------------------------------------
// Phase 3: slot = rank8[e] + prefix[dst]; scattered 4B store, no atomics.
// ---------------------------------------------------------------------------
__global__ __launch_bounds__(256) void scatter_kernel(
    const int* __restrict__ src, const int* __restrict__ dst,
    const unsigned char* __restrict__ rank8, const unsigned int* __restrict__ hist,
    int* __restrict__ ell, int epr, int ndst4, int nb)
{
    __shared__ unsigned int pre4[10240];
    const int r = blockIdx.y, b = blockIdx.x;
    const unsigned int* hp = hist + ((size_t)r * nb + b) * ndst4;
    for (int i = threadIdx.x; i < ndst4; i += 256) pre4[i] = hp[i];
    __syncthreads();
    const int e0 = b * EPB;
    const int ne = min(EPB, epr - e0);
    const size_t eb = (size_t)r * epr + e0;
    const unsigned char* pre = (const unsigned char*)pre4;
    const int ndst = ndst4 * 4;
    for (int i = threadIdx.x; i < ne; i += 256) {
        int d = dst[eb + i];
        int s = src[eb + i];
        int slot = (int)rank8[eb + i] + (int)pre[d];
        if (slot < CAP) ell[((size_t)r * ndst + d) * CAP + slot] = s;
    }
}

// ---------------------------------------------------------------------------
// x (fp32 [N][256]) -> xb (bf16, per-row 16B-chunk XOR-swizzled: c ^= row&7)
// ---------------------------------------------------------------------------
__global__ __launch_bounds__(256) void convx_kernel(
    const float* __restrict__ x, unsigned short* __restrict__ xb)
{
    int id  = blockIdx.x * 256 + threadIdx.x;
    int row = id >> 5;
    int c   = id & 31;
    const float4* xp = (const float4*)(x + ((size_t)row << 8) + (c << 3));
    float4 a = xp[0], b = xp[1];
    u16x4 o0, o1;
    o0.x = f2bf(a.x); o0.y = f2bf(a.y); o0.z = f2bf(a.z); o0.w = f2bf(a.w);
    o1.x = f2bf(b.x); o1.y = f2bf(b.y); o1.z = f2bf(b.z); o1.w = f2bf(b.w);
    int cs = c ^ (row & 7);
    u16x4* op = (u16x4*)(xb + ((size_t)row << 8) + (cs << 3));
    op[0] = o0; op[1] = o1;
}

// ---------------------------------------------------------------------------
// W [R][K][128] fp32 -> WtF: fragment-ordered bf16 B operands.
// frag id f = (r*KS + kki)*8 + nblk; element o = f*512 + lane*8 + j
//   n = nblk*16 + (lane&15), k = kki*32 + (lane>>4)*8 + j
// A wave's B-fragment load is then one contiguous 1KB dwordx4 (coalesced).
// ---------------------------------------------------------------------------
template<int K>
__global__ __launch_bounds__(256) void convwf_kernel(
    const float* __restrict__ W, unsigned short* __restrict__ WtF)
{
    constexpr int KS = K / 32;
    int id = blockIdx.x * 256 + threadIdx.x;       // (frag, lane)
    if (id >= RREL * KS * 8 * 64) return;
    int lane = id & 63;
    int fi   = id >> 6;
    int nblk = fi & 7;
    int rk   = fi >> 3;                            // r*KS + kki
    int kki  = rk & (KS - 1);
    int rr   = rk / KS;
    int n  = nblk * 16 + (lane & 15);
    int k0 = kki * 32 + (lane >> 4) * 8;
    unsigned short* op = WtF + (size_t)id * 8;
    #pragma unroll
    for (int j = 0; j < 8; ++j)
        op[j] = f2bf(W[((size_t)(rr * K + k0 + j)) * 128 + n]);
}

// ---------------------------------------------------------------------------
// GEMM: one block = 128 rows x ALL 512 cols (4 relations). 1024 thr, 16 waves.
// wave = (mh, r, nh) -> 64x64 tile. A staged ONCE (K-phased, counted vmcnt
// so phase-1 staging streams under phase-0 MFMA). B = contiguous 1KB frags.
// ---------------------------------------------------------------------------
template<int K>
__global__ __launch_bounds__(1024, 4) void gemm_kernel(
    const unsigned short* __restrict__ Ab,   // [Mpad][K] bf16, 16B-chunk swizzled
    const unsigned short* __restrict__ WtF,  // fragment-ordered
    unsigned short* __restrict__ Mout, int M)
{
    constexpr int NPH = K / 128;               // 2 (K=256) or 1 (K=128)
    constexpr int KS  = K / 32;
    __shared__ unsigned short As[NPH * 128 * 128];

    const int m0   = blockIdx.x * 128;
    const int tid  = threadIdx.x;
    const int lane = tid & 63;
    const int wave = tid >> 6;                 // 0..15

    // stage all phases up front: per phase 32KB = 2 rounds (1024 thr x 16B)
    const char* gbase = (const char*)Ab;
    #pragma unroll
    for (int h = 0; h < NPH; ++h) {
        #pragma unroll
        for (int j = 0; j < 2; ++j) {
            int L = j * 16384 + tid * 16;
            int row  = L >> 8;
            int boff = L & 255;
            gload_lds16(gbase + ((size_t)(m0 + row) * (K * 2) + h * 256 + boff),
                        (char*)As + h * 32768 + L);
        }
    }

    const int r    = wave & 3;
    const int nh   = (wave >> 2) & 1;
    const int mh   = (wave >> 3) & 1;
    const int wm   = mh * 64;
    const int wn   = nh * 64;
    const int lr   = lane & 15;
    const int kg   = lane >> 4;
    const int xorv = (lr & 7) << 4;
    const unsigned short* Wr = WtF + (size_t)r * KS * 8 * 512;

    f32x4 acc[4][4] = {};
    #pragma unroll
    for (int h = 0; h < NPH; ++h) {
        if (h == 0) {
            if (NPH == 2) asm volatile("s_waitcnt vmcnt(2)" ::: "memory");
            else          asm volatile("s_waitcnt vmcnt(0)" ::: "memory");
        } else {
            asm volatile("s_waitcnt vmcnt(0)" ::: "memory");
        }
        __builtin_amdgcn_s_barrier();
        __builtin_amdgcn_sched_barrier(0);
        const char* Ap = (const char*)As + h * 32768;
        #pragma unroll
        for (int ks = 0; ks < 4; ++ks) {
            bf16x8 af[4], bv[4];
            const int kb = (ks * 64 + kg * 16) ^ xorv;
            #pragma unroll
            for (int mi = 0; mi < 4; ++mi)
                af[mi] = *(const bf16x8*)(Ap + (wm + mi * 16 + lr) * 256 + kb);
            const int kk32 = h * 4 + ks;
            #pragma unroll
            for (int ni = 0; ni < 4; ++ni)
                bv[ni] = *(const bf16x8*)&Wr[((size_t)kk32 * 8 + nh * 4 + ni) * 512 + lane * 8];
            #pragma unroll
            for (int mi = 0; mi < 4; ++mi)
                #pragma unroll
                for (int ni = 0; ni < 4; ++ni)
                    acc[mi][ni] = __builtin_amdgcn_mfma_f32_16x16x32_bf16(
                        af[mi], bv[ni], acc[mi][ni], 0, 0, 0);
        }
    }

    // epilogue: C/D layout col=lane&15, row=(lane>>4)*4+j
    const int rowoff = (lane >> 4) * 4;
    #pragma unroll
    for (int mi = 0; mi < 4; ++mi) {
        #pragma unroll
        for (int j = 0; j < 4; ++j) {
            int grow = m0 + wm + mi * 16 + rowoff + j;
            if (grow < M) {
                #pragma unroll
                for (int ni = 0; ni < 4; ++ni)
                    Mout[(size_t)grow * 512 + r * 128 + wn + ni * 16 + lr]
                        = f2bf(acc[mi][ni][j]);
            }
        }
    }
}

// ---------------------------------------------------------------------------
// Gather: block per dst node, wave w handles relation w.
// 8 edges/iter, lane-halves split across edge pairs (4 x dwordx2 in flight).
// ---------------------------------------------------------------------------
template<bool OUT_F32>
__global__ __launch_bounds__(256) void gather_kernel(
    const unsigned short* __restrict__ Mt,   // [n_src_side][512] bf16
    const int* __restrict__ ell, const int* __restrict__ cnt,
    const float* __restrict__ bias,          // [R][128]
    void* __restrict__ outp, int ndst)
{
    __shared__ float red[RREL][2][128];
    const int node = blockIdx.x;
    const int lane = threadIdx.x & 63;
    const int r    = threadIdx.x >> 6;
    const int half = lane >> 5;
    const int sub  = lane & 31;
    const int idx  = r * ndst + node;
    const int c    = cnt[idx];
    const int deg  = c < CAP ? c : CAP;
    const int base = idx * CAP;
    const int coff = r * 128 + sub * 4;      // element offset; 8B per lane

    float a0 = 0.f, a1 = 0.f, a2 = 0.f, a3 = 0.f;
    int e = 0;
    for (; e + 8 <= deg; e += 8) {
        int4 sa = *(const int4*)&ell[base + e];
        int4 sb = *(const int4*)&ell[base + e + 4];
        int sA = half ? sa.y : sa.x;
        int sB = half ? sa.w : sa.z;
        int sC = half ? sb.y : sb.x;
        int sD = half ? sb.w : sb.z;
        uint2 v0 = *(const uint2*)&Mt[(size_t)sA * 512 + coff];
        uint2 v1 = *(const uint2*)&Mt[(size_t)sB * 512 + coff];
        uint2 v2 = *(const uint2*)&Mt[(size_t)sC * 512 + coff];
        uint2 v3 = *(const uint2*)&Mt[(size_t)sD * 512 + coff];
        a0 += bflo(v0.x) + bflo(v1.x) + bflo(v2.x) + bflo(v3.x);
        a1 += bfhi(v0.x) + bfhi(v1.x) + bfhi(v2.x) + bfhi(v3.x);
        a2 += bflo(v0.y) + bflo(v1.y) + bflo(v2.y) + bflo(v3.y);
        a3 += bfhi(v0.y) + bfhi(v1.y) + bfhi(v2.y) + bfhi(v3.y);
    }
    for (; e < deg; e += 2) {
        int s0 = ell[base + e];
        int s1 = (e + 1 < deg) ? ell[base + e + 1] : -1;
        int s = half ? s1 : s0;
        if (s >= 0) {
            uint2 v = *(const uint2*)&Mt[(size_t)s * 512 + coff];
            a0 += bflo(v.x); a1 += bfhi(v.x);
            a2 += bflo(v.y); a3 += bfhi(v.y);
        }
    }
    float norm = c > 0 ? 1.0f / (float)c : 0.0f;
    red[r][half][sub * 4 + 0] = a0 * norm;
    red[r][half][sub * 4 + 1] = a1 * norm;
    red[r][half][sub * 4 + 2] = a2 * norm;
    red[r][half][sub * 4 + 3] = a3 * norm;
    __syncthreads();

    const int t = threadIdx.x;
    if (t < 128) {
        float s = red[0][0][t] + red[0][1][t] + red[1][0][t] + red[1][1][t]
                + red[2][0][t] + red[2][1][t] + red[3][0][t] + red[3][1][t]
                + bias[t] + bias[128 + t] + bias[256 + t] + bias[384 + t];
        if constexpr (OUT_F32) {
            ((float*)outp)[node * 128 + t] = s;
        } else {
            int cs = ((t >> 3) ^ (node & 7)) << 3;           // swizzled h layout
            ((unsigned short*)outp)[node * 128 + cs + (t & 7)] = f2bf(s);
        }
    }
}

// ---------------------------------------------------------------------------
extern "C" void kernel_launch(void* const* d_in, const int* in_sizes, int n_in,
                              void* d_out, int out_size, void* d_ws, size_t ws_size,
                              hipStream_t stream)
{
    const float* x  = (const float*)d_in[0];
    const float* W1 = (const float*)d_in[1];
    const float* b1 = (const float*)d_in[2];
    const float* W2 = (const float*)d_in[3];
    const float* b2 = (const float*)d_in[4];
    const int* src1 = (const int*)d_in[5];
    const int* dst1 = (const int*)d_in[6];
    const int* src2 = (const int*)d_in[7];
    const int* dst2 = (const int*)d_in[8];

    char* p = (char*)d_ws;
    auto alloc = [&](size_t bytes) {
        char* q = p; p += (bytes + 255) & ~(size_t)255; return q;
    };
    unsigned short* xb   = (unsigned short*)alloc((size_t)(N_SRC + 64) * 256 * 2);  // 102.4 MB
    unsigned short* m1   = (unsigned short*)alloc((size_t)N_SRC * 512 * 2);         // 204.8 MB
    int*            ell1 = (int*)alloc((size_t)RREL * N_MIDN * CAP * 4);            //  61.4 MB
    int*            cnt1 = (int*)alloc((size_t)RREL * N_MIDN * 4);
    unsigned short* h    = (unsigned short*)alloc((size_t)(N_MIDN + 64) * 128 * 2); //  10.3 MB
    unsigned short* wt1  = (unsigned short*)alloc((size_t)RREL * 8 * 8 * 64 * 8 * 2);  // 256 KB frag-ordered
    unsigned short* wt2  = (unsigned short*)alloc((size_t)RREL * 4 * 8 * 64 * 8 * 2);  // 128 KB
    // Layer-2 scratch aliases xb (xb dead after gemm1):
    char* q2 = (char*)xb;
    unsigned short* m2   = (unsigned short*)q2; q2 += (size_t)N_MIDN * 512 * 2;     //  41.0 MB
    int*            ell2 = (int*)q2;            q2 += (size_t)RREL * N_DSTN * CAP * 4;
    int*            cnt2 = (int*)q2;
    // Fill scratch aliases m1 (dead until gemm1 / after gather1):
    const int NB1 = (E1N + EPB - 1) / EPB;   // 123
    const int NB2 = (E2N + EPB - 1) / EPB;   // 25
    unsigned int*  hist  = (unsigned int*)m1;                          // <= 19.7 MB
    unsigned char* rank8 = (unsigned char*)m1 + 24 * 1024 * 1024;      // 4 MB

    convwf_kernel<256><<<64, 256, 0, stream>>>(W1, wt1);
    convwf_kernel<128><<<32, 256, 0, stream>>>(W2, wt2);
    convx_kernel<<<(N_SRC * 32) / 256, 256, 0, stream>>>(x, xb);

    // layer-1 ELL build (atomic-free counting sort)
    count_kernel  <<<dim3(NB1, RREL), 256, 0, stream>>>(dst1, rank8, hist, E1N, N_MIDN / 4, NB1);
    scan_kernel   <<<(RREL * N_MIDN + 255) / 256, 256, 0, stream>>>(hist, cnt1, N_MIDN, N_MIDN / 4, NB1);
    scatter_kernel<<<dim3(NB1, RREL), 256, 0, stream>>>(src1, dst1, rank8, hist, ell1, E1N, N_MIDN / 4, NB1);

    gemm_kernel<256><<<(N_SRC + 127) / 128, 1024, 0, stream>>>(xb, wt1, m1, N_SRC);
    gather_kernel<false><<<N_MIDN, 256, 0, stream>>>(m1, ell1, cnt1, b1, (void*)h, N_MIDN);

    // layer-2 ELL build (hist/rank8 reuse m1 space; ell2/cnt2 alias xb)
    count_kernel  <<<dim3(NB2, RREL), 256, 0, stream>>>(dst2, rank8, hist, E2N, N_DSTN / 4, NB2);
    scan_kernel   <<<(RREL * N_DSTN + 255) / 256, 256, 0, stream>>>(hist, cnt2, N_DSTN, N_DSTN / 4, NB2);
    scatter_kernel<<<dim3(NB2, RREL), 256, 0, stream>>>(src2, dst2, rank8, hist, ell2, E2N, N_DSTN / 4, NB2);

    gemm_kernel<128><<<(N_MIDN + 127) / 128, 1024, 0, stream>>>(h, wt2, m2, N_MIDN);
    gather_kernel<true><<<N_DSTN, 256, 0, stream>>>(m2, ell2, cnt2, b2, d_out, N_DSTN);
}